// Round 8
// baseline (122.042 us; speedup 1.0000x reference)
//
#include <hip/hip_runtime.h>

#define N_NODES 10000
#define D 128
#define N_EDGES 640000
#define NB 128                 // histogram blocks
#define EPB (N_EDGES / NB)     // 5000 edges per block
#define SB 40                  // scan blocks
#define NPSB 250               // nodes per scan block

typedef __attribute__((ext_vector_type(8))) short bf16x8;          // MFMA A/B frag
typedef __attribute__((ext_vector_type(4))) float f32x4;           // MFMA acc
typedef __attribute__((ext_vector_type(8))) unsigned short us8;    // 16B bf16 row chunk
typedef __attribute__((ext_vector_type(8))) float f32x8;
typedef __attribute__((ext_vector_type(4))) unsigned int u32x4;

// ---------------- fp32 -> bf16 (round-to-nearest-even) ----------------

__device__ __forceinline__ unsigned short f2bf(float f) {
    union { float f; unsigned int i; } v;
    v.f = f;
    unsigned int b = v.i;
    unsigned int rounded = b + 0x7fffu + ((b >> 16) & 1u);
    return (unsigned short)(rounded >> 16);
}

__device__ __forceinline__ float asf(unsigned int u) {
    union { unsigned int i; float f; } v;
    v.i = u;
    return v.f;
}

// ---------------- K1: fused cast + PACKED LDS histogram (verified R7) -------------

__global__ __launch_bounds__(1024) void hist_cast_kernel(const int* __restrict__ ei,
                                                         const float4* __restrict__ x4,
                                                         const float4* __restrict__ Wl4,
                                                         const float4* __restrict__ Wr4,
                                                         ushort4* __restrict__ xh4,
                                                         ushort4* __restrict__ Wlb4,
                                                         ushort4* __restrict__ Wrb4,
                                                         unsigned short* __restrict__ lrank,
                                                         unsigned short* __restrict__ cnt,
                                                         unsigned long long* __restrict__ flags) {
    __shared__ unsigned int h[N_NODES / 2];          // packed: node n -> word n>>1, half n&1
    for (int w = threadIdx.x; w < N_NODES / 2; w += 1024) h[w] = 0u;
    if (blockIdx.x == 0 && threadIdx.x < SB) flags[threadIdx.x] = 0ULL;

    const int gid = blockIdx.x * 1024 + threadIdx.x;      // 131072 threads
    for (int i = gid; i < N_NODES * D / 4; i += NB * 1024) {
        float4 v = x4[i];
        ushort4 o;
        o.x = f2bf(v.x); o.y = f2bf(v.y); o.z = f2bf(v.z); o.w = f2bf(v.w);
        xh4[i] = o;
    }
    if (gid < D * D / 4) {
        float4 a = Wl4[gid], b = Wr4[gid];
        ushort4 oa, ob;
        oa.x = f2bf(a.x); oa.y = f2bf(a.y); oa.z = f2bf(a.z); oa.w = f2bf(a.w);
        ob.x = f2bf(b.x); ob.y = f2bf(b.y); ob.z = f2bf(b.z); ob.w = f2bf(b.w);
        Wlb4[gid] = oa;
        Wrb4[gid] = ob;
    }
    __syncthreads();

    const int base = blockIdx.x * EPB;
    for (int e = base + threadIdx.x; e < base + EPB; e += 1024) {
        int d = ei[N_EDGES + e];                     // row 1 = dst
        int sh = (d & 1) << 4;
        unsigned int old = atomicAdd(&h[d >> 1], 1u << sh);
        lrank[e] = (unsigned short)((old >> sh) & 0xffffu);
    }
    __syncthreads();
    unsigned int* c = (unsigned int*)(cnt + (size_t)blockIdx.x * N_NODES);
    for (int w = threadIdx.x; w < N_NODES / 2; w += 1024) c[w] = h[w];
}

// ---------------- K2: fused column scan + node scan (verified baseline) -----------

__global__ __launch_bounds__(256) void colscan_scan_kernel(unsigned short* __restrict__ cnt,
                                                           int* __restrict__ row_start,
                                                           unsigned long long* __restrict__ flags) {
    const int t = threadIdx.x;
    const int b = blockIdx.x;
    const int n = b * NPSB + t;            // valid for t < NPSB
    __shared__ int sc[256];
    __shared__ int blk_excl_sh;

    int deg = 0;
    if (t < NPSB) {
        int s = 0;
#pragma unroll 8
        for (int j = 0; j < NB; ++j) {
            int idx = j * N_NODES + n;
            int v = cnt[idx];
            cnt[idx] = (unsigned short)s;
            s += v;
        }
        deg = s;
    }
    sc[t] = deg;
    __syncthreads();
    for (int off = 1; off < 256; off <<= 1) {
        int v = (t >= off) ? sc[t - off] : 0;
        __syncthreads();
        sc[t] += v;
        __syncthreads();
    }
    const int total = sc[255];
    const int local_excl = sc[t] - deg;

    if (t == 0) {
        int excl = 0;
        if (b == 0) {
            __hip_atomic_store(&flags[0], (2ULL << 32) | (unsigned)total,
                               __ATOMIC_RELEASE, __HIP_MEMORY_SCOPE_AGENT);
        } else {
            __hip_atomic_store(&flags[b], (1ULL << 32) | (unsigned)total,
                               __ATOMIC_RELEASE, __HIP_MEMORY_SCOPE_AGENT);
            int j = b - 1;
            while (j >= 0) {
                unsigned long long f = __hip_atomic_load(&flags[j], __ATOMIC_ACQUIRE,
                                                         __HIP_MEMORY_SCOPE_AGENT);
                unsigned st = (unsigned)(f >> 32);
                if (st == 0) continue;
                excl += (int)(unsigned)(f & 0xffffffffULL);
                if (st == 2) break;
                --j;
            }
            __hip_atomic_store(&flags[b], (2ULL << 32) | (unsigned)(excl + total),
                               __ATOMIC_RELEASE, __HIP_MEMORY_SCOPE_AGENT);
        }
        blk_excl_sh = excl;
    }
    __syncthreads();
    if (t < NPSB) row_start[n] = blk_excl_sh + local_excl;
    if (b == SB - 1 && t == 0) row_start[N_NODES] = N_EDGES;
}

// ---------------- K3: scatter (verified baseline) ----------------

__global__ __launch_bounds__(256) void scatter_kernel(const int* __restrict__ ei,
                                                      const int* __restrict__ row_start,
                                                      const unsigned short* __restrict__ cnt,
                                                      const unsigned short* __restrict__ lrank,
                                                      unsigned short* __restrict__ csr) {
    int i = blockIdx.x * 256 + threadIdx.x;
    if (i < N_EDGES) {
        int b = i / EPB;
        int s = ei[i];
        int d = ei[N_EDGES + i];
        int pos = row_start[d] + (int)cnt[b * N_NODES + d] + (int)lrank[i];
        csr[pos] = (unsigned short)s;
    }
}

// ---------------- K4: mean aggregation, wave-per-node, split accumulators ---------
// Per uint (2 bf16): accHi += as_float(u) (low ushort = mantissa garbage, <2^-7 rel,
// vanishes after mean), accLo += as_float(u<<16) (exact). 3 VALU ops / 2 elements
// instead of 4. Cross-slot reduce via 2 shuffle-xor steps; no LDS, no barriers.

__global__ __launch_bounds__(256) void aggregate_kernel(const us8* __restrict__ xh8,
                                                        const int* __restrict__ row_start,
                                                        const unsigned short* __restrict__ csr,
                                                        us8* __restrict__ aggb8) {
    const int node = blockIdx.x * 4 + (threadIdx.x >> 6);
    const int lane = threadIdx.x & 63;
    const int lane16 = lane & 15;          // feature octet
    const int slot = lane >> 4;            // edge slot 0..3
    const int start = row_start[node];
    const int end = row_start[node + 1];
    const u32x4* xu = (const u32x4*)xh8;

    f32x4 h0 = 0.f, l0 = 0.f, h1 = 0.f, l1 = 0.f;
    f32x4 h2 = 0.f, l2 = 0.f, h3 = 0.f, l3 = 0.f;
    int j = start + slot;
    for (; j + 12 < end; j += 16) {
        int s0 = csr[j], s1 = csr[j + 4], s2 = csr[j + 8], s3 = csr[j + 12];
        u32x4 v0 = xu[s0 * 16 + lane16];
        u32x4 v1 = xu[s1 * 16 + lane16];
        u32x4 v2 = xu[s2 * 16 + lane16];
        u32x4 v3 = xu[s3 * 16 + lane16];
#pragma unroll
        for (int t = 0; t < 4; ++t) {
            h0[t] += asf(v0[t]); l0[t] += asf(v0[t] << 16);
            h1[t] += asf(v1[t]); l1[t] += asf(v1[t] << 16);
            h2[t] += asf(v2[t]); l2[t] += asf(v2[t] << 16);
            h3[t] += asf(v3[t]); l3[t] += asf(v3[t] << 16);
        }
    }
    for (; j < end; j += 4) {
        u32x4 v = xu[(int)csr[j] * 16 + lane16];
#pragma unroll
        for (int t = 0; t < 4; ++t) {
            h0[t] += asf(v[t]); l0[t] += asf(v[t] << 16);
        }
    }
    f32x4 H = (h0 + h1) + (h2 + h3);
    f32x4 L = (l0 + l1) + (l2 + l3);

    f32x8 r;
#pragma unroll
    for (int t = 0; t < 4; ++t) { r[t] = L[t]; r[4 + t] = H[t]; }
#pragma unroll
    for (int t = 0; t < 8; ++t) {          // combine slots: lanes xor 16, then xor 32
        float v = r[t];
        v += __shfl_xor(v, 16, 64);
        v += __shfl_xor(v, 32, 64);
        r[t] = v;
    }
    if (slot == 0) {
        int cE = end - start;
        float inv = (cE > 0) ? 1.0f / (float)cE : 0.0f;
        us8 pack;
#pragma unroll
        for (int t = 0; t < 4; ++t) {
            pack[2 * t]     = f2bf(r[t] * inv);        // even feature (lo ushort)
            pack[2 * t + 1] = f2bf(r[4 + t] * inv);    // odd feature (hi ushort)
        }
        aggb8[node * 16 + lane16] = pack;
    }
}

// ---------------- K5: SAGE linear + residual, 2 M-tiles per wave ------------------
// Wave handles C-tiles {mt0, mt0+1} x one 16-col tile: W frags loaded once, two
// independent MFMA chains. grid = (79, 8).

__global__ __launch_bounds__(256) void lin_mfma_kernel(const float* __restrict__ x,
                                                       const unsigned short* __restrict__ aggb,
                                                       const unsigned short* __restrict__ xh,
                                                       const unsigned short* __restrict__ Wlb,
                                                       const unsigned short* __restrict__ Wrb,
                                                       const float* __restrict__ bl,
                                                       float* __restrict__ out) {
    const int wave = threadIdx.x >> 6;
    const int lane = threadIdx.x & 63;
    const int l15 = lane & 15;
    const int quad = lane >> 4;
    const int mt0 = blockIdx.x * 8 + wave * 2;       // even tiles 0..630
    if (mt0 >= 625) return;
    const int mt1 = (mt0 + 1 < 625) ? mt0 + 1 : mt0; // clamp; tile1 stores guarded
    const int row0 = mt0 * 16;
    const int row1 = mt1 * 16;
    const int out0 = blockIdx.y * 16;
    const int f = out0 + l15;

    const bf16x8* a0r = (const bf16x8*)(aggb + (size_t)(row0 + l15) * D) + quad;
    const bf16x8* x0r = (const bf16x8*)(xh   + (size_t)(row0 + l15) * D) + quad;
    const bf16x8* a1r = (const bf16x8*)(aggb + (size_t)(row1 + l15) * D) + quad;
    const bf16x8* x1r = (const bf16x8*)(xh   + (size_t)(row1 + l15) * D) + quad;
    const bf16x8* wlro = (const bf16x8*)(Wlb + (size_t)f * D) + quad;
    const bf16x8* wrro = (const bf16x8*)(Wrb + (size_t)f * D) + quad;

    f32x4 c0 = {0.f, 0.f, 0.f, 0.f};
    f32x4 c1 = {0.f, 0.f, 0.f, 0.f};
#pragma unroll
    for (int kk = 0; kk < 4; ++kk) {
        bf16x8 wlF = wlro[kk * 4];
        bf16x8 wrF = wrro[kk * 4];
        c0 = __builtin_amdgcn_mfma_f32_16x16x32_bf16(a0r[kk * 4], wlF, c0, 0, 0, 0);
        c0 = __builtin_amdgcn_mfma_f32_16x16x32_bf16(x0r[kk * 4], wrF, c0, 0, 0, 0);
        c1 = __builtin_amdgcn_mfma_f32_16x16x32_bf16(a1r[kk * 4], wlF, c1, 0, 0, 0);
        c1 = __builtin_amdgcn_mfma_f32_16x16x32_bf16(x1r[kk * 4], wrF, c1, 0, 0, 0);
    }

    const float bias = bl[f];
#pragma unroll
    for (int r = 0; r < 4; ++r) {
        int row = row0 + quad * 4 + r;
        int idx = row * D + f;
        out[idx] = x[idx] + bias + c0[r];
    }
    if (mt0 + 1 < 625) {
#pragma unroll
        for (int r = 0; r < 4; ++r) {
            int row = row1 + quad * 4 + r;
            int idx = row * D + f;
            out[idx] = x[idx] + bias + c1[r];
        }
    }
}

extern "C" void kernel_launch(void* const* d_in, const int* in_sizes, int n_in,
                              void* d_out, int out_size, void* d_ws, size_t ws_size,
                              hipStream_t stream) {
    const float* x  = (const float*)d_in[0];
    const int*   ei = (const int*)d_in[1];     // [2, E] int32
    const float* Wl = (const float*)d_in[2];
    const float* bl = (const float*)d_in[3];
    const float* Wr = (const float*)d_in[4];
    float* out = (float*)d_out;

    // workspace layout (16B-aligned segments)
    unsigned long long* flags = (unsigned long long*)d_ws;               // 64 ULL
    int* row_start = (int*)(flags + 64);                                 // 10016 ints
    unsigned short* cnt   = (unsigned short*)(row_start + 10016);        // NB*N_NODES us
    unsigned short* lrank = cnt + (size_t)NB * N_NODES;                  // N_EDGES us
    unsigned short* csr   = lrank + N_EDGES;                             // N_EDGES us
    unsigned short* xh    = csr + N_EDGES;                               // N_NODES*D (bf16)
    unsigned short* aggb  = xh + (size_t)N_NODES * D;                    // N_NODES*D (bf16)
    unsigned short* Wlb   = aggb + (size_t)N_NODES * D;                  // D*D (bf16)
    unsigned short* Wrb   = Wlb + D * D;                                 // D*D (bf16)

    hist_cast_kernel<<<NB, 1024, 0, stream>>>(ei, (const float4*)x, (const float4*)Wl,
                                              (const float4*)Wr, (ushort4*)xh,
                                              (ushort4*)Wlb, (ushort4*)Wrb,
                                              lrank, cnt, flags);
    colscan_scan_kernel<<<SB, 256, 0, stream>>>(cnt, row_start, flags);
    scatter_kernel<<<(N_EDGES + 255) / 256, 256, 0, stream>>>(ei, row_start, cnt, lrank, csr);
    aggregate_kernel<<<2500, 256, 0, stream>>>((const us8*)xh, row_start, csr,
                                               (us8*)aggb);
    lin_mfma_kernel<<<dim3(79, 8), 256, 0, stream>>>(x, aggb, xh, Wlb, Wrb, bl, out);
}

// Round 9
// 121.520 us; speedup vs baseline: 1.0043x; 1.0043x over previous
//
#include <hip/hip_runtime.h>

#define N_NODES 10000
#define D 128
#define N_EDGES 640000
#define NB 128                 // histogram blocks
#define EPB (N_EDGES / NB)     // 5000 edges per block
#define SB 40                  // scan blocks
#define NPSB 250               // nodes per scan block

typedef __attribute__((ext_vector_type(8))) short bf16x8;          // MFMA A/B frag
typedef __attribute__((ext_vector_type(4))) float f32x4;           // MFMA acc
typedef __attribute__((ext_vector_type(8))) unsigned short us8;    // 16B bf16 row chunk
typedef __attribute__((ext_vector_type(8))) float f32x8;

// ---------------- fp32 -> bf16 (round-to-nearest-even) ----------------

__device__ __forceinline__ unsigned short f2bf(float f) {
    union { float f; unsigned int i; } v;
    v.f = f;
    unsigned int b = v.i;
    unsigned int rounded = b + 0x7fffu + ((b >> 16) & 1u);
    return (unsigned short)(rounded >> 16);
}

__device__ __forceinline__ float bf2f(unsigned short u) {
    union { unsigned int i; float f; } v;
    v.i = ((unsigned int)u) << 16;
    return v.f;
}

__device__ __forceinline__ f32x8 bf2f8(us8 v) {
    f32x8 r;
#pragma unroll
    for (int t = 0; t < 8; ++t) r[t] = bf2f(v[t]);
    return r;
}

// ---------------- K1: fused cast + PACKED LDS histogram (verified R7) -------------

__global__ __launch_bounds__(1024) void hist_cast_kernel(const int* __restrict__ ei,
                                                         const float4* __restrict__ x4,
                                                         const float4* __restrict__ Wl4,
                                                         const float4* __restrict__ Wr4,
                                                         ushort4* __restrict__ xh4,
                                                         ushort4* __restrict__ Wlb4,
                                                         ushort4* __restrict__ Wrb4,
                                                         unsigned short* __restrict__ lrank,
                                                         unsigned short* __restrict__ cnt,
                                                         unsigned long long* __restrict__ flags) {
    __shared__ unsigned int h[N_NODES / 2];          // packed: node n -> word n>>1, half n&1
    for (int w = threadIdx.x; w < N_NODES / 2; w += 1024) h[w] = 0u;
    if (blockIdx.x == 0 && threadIdx.x < SB) flags[threadIdx.x] = 0ULL;

    const int gid = blockIdx.x * 1024 + threadIdx.x;      // 131072 threads
    for (int i = gid; i < N_NODES * D / 4; i += NB * 1024) {
        float4 v = x4[i];
        ushort4 o;
        o.x = f2bf(v.x); o.y = f2bf(v.y); o.z = f2bf(v.z); o.w = f2bf(v.w);
        xh4[i] = o;
    }
    if (gid < D * D / 4) {
        float4 a = Wl4[gid], b = Wr4[gid];
        ushort4 oa, ob;
        oa.x = f2bf(a.x); oa.y = f2bf(a.y); oa.z = f2bf(a.z); oa.w = f2bf(a.w);
        ob.x = f2bf(b.x); ob.y = f2bf(b.y); ob.z = f2bf(b.z); ob.w = f2bf(b.w);
        Wlb4[gid] = oa;
        Wrb4[gid] = ob;
    }
    __syncthreads();

    const int base = blockIdx.x * EPB;
    for (int e = base + threadIdx.x; e < base + EPB; e += 1024) {
        int d = ei[N_EDGES + e];                     // row 1 = dst
        int sh = (d & 1) << 4;
        unsigned int old = atomicAdd(&h[d >> 1], 1u << sh);
        lrank[e] = (unsigned short)((old >> sh) & 0xffffu);
    }
    __syncthreads();
    unsigned int* c = (unsigned int*)(cnt + (size_t)blockIdx.x * N_NODES);
    for (int w = threadIdx.x; w < N_NODES / 2; w += 1024) c[w] = h[w];
}

// ---------------- K2: fused column scan + node scan (verified baseline) -----------

__global__ __launch_bounds__(256) void colscan_scan_kernel(unsigned short* __restrict__ cnt,
                                                           int* __restrict__ row_start,
                                                           unsigned long long* __restrict__ flags) {
    const int t = threadIdx.x;
    const int b = blockIdx.x;
    const int n = b * NPSB + t;            // valid for t < NPSB
    __shared__ int sc[256];
    __shared__ int blk_excl_sh;

    int deg = 0;
    if (t < NPSB) {
        int s = 0;
#pragma unroll 8
        for (int j = 0; j < NB; ++j) {
            int idx = j * N_NODES + n;
            int v = cnt[idx];
            cnt[idx] = (unsigned short)s;
            s += v;
        }
        deg = s;
    }
    sc[t] = deg;
    __syncthreads();
    for (int off = 1; off < 256; off <<= 1) {
        int v = (t >= off) ? sc[t - off] : 0;
        __syncthreads();
        sc[t] += v;
        __syncthreads();
    }
    const int total = sc[255];
    const int local_excl = sc[t] - deg;

    if (t == 0) {
        int excl = 0;
        if (b == 0) {
            __hip_atomic_store(&flags[0], (2ULL << 32) | (unsigned)total,
                               __ATOMIC_RELEASE, __HIP_MEMORY_SCOPE_AGENT);
        } else {
            __hip_atomic_store(&flags[b], (1ULL << 32) | (unsigned)total,
                               __ATOMIC_RELEASE, __HIP_MEMORY_SCOPE_AGENT);
            int j = b - 1;
            while (j >= 0) {
                unsigned long long f = __hip_atomic_load(&flags[j], __ATOMIC_ACQUIRE,
                                                         __HIP_MEMORY_SCOPE_AGENT);
                unsigned st = (unsigned)(f >> 32);
                if (st == 0) continue;
                excl += (int)(unsigned)(f & 0xffffffffULL);
                if (st == 2) break;
                --j;
            }
            __hip_atomic_store(&flags[b], (2ULL << 32) | (unsigned)(excl + total),
                               __ATOMIC_RELEASE, __HIP_MEMORY_SCOPE_AGENT);
        }
        blk_excl_sh = excl;
    }
    __syncthreads();
    if (t < NPSB) row_start[n] = blk_excl_sh + local_excl;
    if (b == SB - 1 && t == 0) row_start[N_NODES] = N_EDGES;
}

// ---------------- K3: scatter (verified baseline) ----------------

__global__ __launch_bounds__(256) void scatter_kernel(const int* __restrict__ ei,
                                                      const int* __restrict__ row_start,
                                                      const unsigned short* __restrict__ cnt,
                                                      const unsigned short* __restrict__ lrank,
                                                      unsigned short* __restrict__ csr) {
    int i = blockIdx.x * 256 + threadIdx.x;
    if (i < N_EDGES) {
        int b = i / EPB;
        int s = ei[i];
        int d = ei[N_EDGES + i];
        int pos = row_start[d] + (int)cnt[b * N_NODES + d] + (int)lrank[i];
        csr[pos] = (unsigned short)s;
    }
}

// ---------------- K4: fused wave-per-node aggregation + SAGE MFMA -----------------
// 625 blocks x 1024 threads. Wave w (0..15) aggregates node blockIdx*16+w using
// R7's verified 16-lane x 4-slot gather + shuffle reduce (no serialization, no
// barriers). Result rows go to padded LDS tile; ONE barrier; waves 0..7 each run
// a 16x16 col-tile of the MFMA (A from LDS, xh/W from L2). Kills the aggb
// round-trip and the 5th dispatch.

__global__ __launch_bounds__(1024) void agg_lin_kernel(const us8* __restrict__ xh8,
                                                       const int* __restrict__ row_start,
                                                       const unsigned short* __restrict__ csr,
                                                       const float* __restrict__ x,
                                                       const unsigned short* __restrict__ xh,
                                                       const unsigned short* __restrict__ Wlb,
                                                       const unsigned short* __restrict__ Wrb,
                                                       const float* __restrict__ bl,
                                                       float* __restrict__ out) {
    __shared__ unsigned short aggT[16][136];   // row stride 272B: 2-way bank alias (free)
    const int wave = threadIdx.x >> 6;         // 0..15 = node within tile
    const int lane = threadIdx.x & 63;
    const int lane16 = lane & 15;              // feature octet
    const int slot = lane >> 4;                // edge slot 0..3
    const int quad = lane >> 4;
    const int l15 = lane & 15;
    const int row0 = blockIdx.x * 16;
    const int node = row0 + wave;

    // ---- aggregate (R7 body, byte-identical math) ----
    const int start = row_start[node];
    const int end = row_start[node + 1];
    f32x8 a0 = 0.f, a1 = 0.f, a2 = 0.f, a3 = 0.f;
    int j = start + slot;
    for (; j + 12 < end; j += 16) {
        int s0 = csr[j], s1 = csr[j + 4], s2 = csr[j + 8], s3 = csr[j + 12];
        a0 += bf2f8(xh8[s0 * 16 + lane16]);
        a1 += bf2f8(xh8[s1 * 16 + lane16]);
        a2 += bf2f8(xh8[s2 * 16 + lane16]);
        a3 += bf2f8(xh8[s3 * 16 + lane16]);
    }
    for (; j < end; j += 4) a0 += bf2f8(xh8[(int)csr[j] * 16 + lane16]);
    a0 = (a0 + a1) + (a2 + a3);

#pragma unroll
    for (int t = 0; t < 8; ++t) {              // combine slots: lanes xor 16, then xor 32
        float v = a0[t];
        v += __shfl_xor(v, 16, 64);
        v += __shfl_xor(v, 32, 64);
        a0[t] = v;
    }
    if (slot == 0) {
        int cE = end - start;
        float inv = (cE > 0) ? 1.0f / (float)cE : 0.0f;
        us8 pack;
#pragma unroll
        for (int t = 0; t < 8; ++t) pack[t] = f2bf(a0[t] * inv);
        *(us8*)&aggT[wave][lane16 * 8] = pack; // 16 lanes -> 256B contiguous row
    }
    __syncthreads();                           // aggT complete

    // ---- MFMA: waves 0..7 each compute 16 rows x 16 cols (col-tile = wave) ----
    if (wave < 8) {
        const int f = wave * 16 + l15;
        const unsigned short* ap = &aggT[l15][quad * 8];
        const bf16x8* xrow = (const bf16x8*)(xh + (size_t)(row0 + l15) * D) + quad;
        const bf16x8* wlro = (const bf16x8*)(Wlb + (size_t)f * D) + quad;
        const bf16x8* wrro = (const bf16x8*)(Wrb + (size_t)f * D) + quad;

        f32x4 c = {0.f, 0.f, 0.f, 0.f};
#pragma unroll
        for (int kk = 0; kk < 4; ++kk) {
            bf16x8 af = *(const bf16x8*)(ap + kk * 32);
            c = __builtin_amdgcn_mfma_f32_16x16x32_bf16(af, wlro[kk * 4], c, 0, 0, 0);
            c = __builtin_amdgcn_mfma_f32_16x16x32_bf16(xrow[kk * 4], wrro[kk * 4], c, 0, 0, 0);
        }

        const float bias = bl[f];
#pragma unroll
        for (int r = 0; r < 4; ++r) {
            int row = row0 + quad * 4 + r;
            int idx = row * D + f;
            out[idx] = x[idx] + bias + c[r];
        }
    }
}

extern "C" void kernel_launch(void* const* d_in, const int* in_sizes, int n_in,
                              void* d_out, int out_size, void* d_ws, size_t ws_size,
                              hipStream_t stream) {
    const float* x  = (const float*)d_in[0];
    const int*   ei = (const int*)d_in[1];     // [2, E] int32
    const float* Wl = (const float*)d_in[2];
    const float* bl = (const float*)d_in[3];
    const float* Wr = (const float*)d_in[4];
    float* out = (float*)d_out;

    // workspace layout (16B-aligned segments)
    unsigned long long* flags = (unsigned long long*)d_ws;               // 64 ULL
    int* row_start = (int*)(flags + 64);                                 // 10016 ints
    unsigned short* cnt   = (unsigned short*)(row_start + 10016);        // NB*N_NODES us
    unsigned short* lrank = cnt + (size_t)NB * N_NODES;                  // N_EDGES us
    unsigned short* csr   = lrank + N_EDGES;                             // N_EDGES us
    unsigned short* xh    = csr + N_EDGES;                               // N_NODES*D (bf16)
    unsigned short* Wlb   = xh + (size_t)N_NODES * D;                    // D*D (bf16)
    unsigned short* Wrb   = Wlb + D * D;                                 // D*D (bf16)

    hist_cast_kernel<<<NB, 1024, 0, stream>>>(ei, (const float4*)x, (const float4*)Wl,
                                              (const float4*)Wr, (ushort4*)xh,
                                              (ushort4*)Wlb, (ushort4*)Wrb,
                                              lrank, cnt, flags);
    colscan_scan_kernel<<<SB, 256, 0, stream>>>(cnt, row_start, flags);
    scatter_kernel<<<(N_EDGES + 255) / 256, 256, 0, stream>>>(ei, row_start, cnt, lrank, csr);
    agg_lin_kernel<<<625, 1024, 0, stream>>>((const us8*)xh, row_start, csr,
                                             x, xh, Wlb, Wrb, bl, out);
}